// Round 15
// baseline (539.994 us; speedup 1.0000x reference)
//
#include <hip/hip_runtime.h>
#include <hip/hip_cooperative_groups.h>
#include <cmath>

namespace cg = cooperative_groups;

#define R_LEVELS 16
#define N_TAB    524288u
#define N_MASK   (N_TAB - 1u)
#define PRIME_H  2654435761u
#define M_PTS    1048576
#define BDIM     128              // buckets per axis
#define NBUCK    (BDIM * BDIM)    // 16384 Morton buckets
#define NB4      (NBUCK / 4)      // packed u32 groups = 4096
#define SBLK     256              // sort blocks (1 per CU, co-resident)
#define STHR     1024
#define SPB      (M_PTS / SBLK)   // 4096
#define SITER    (SPB / STHR)     // 4
#define NSEG     32               // scanw segments
#define WSEG     (SBLK / NSEG)    // 8 blocks per segment
#define XSTRIDE  36               // bf16 elems per LDS row: 32 ch + 4 pad (72 B)
#define NFRAG    384              // 6 (layer,kc) x 64 lanes

typedef __attribute__((ext_vector_type(8)))  short bf16x8;
typedef __attribute__((ext_vector_type(16))) float f32x16;

union FragU { bf16x8 v; uint4 q; unsigned u[4]; uint2 u2[2]; unsigned short s[8]; };

struct ResArr { float r[R_LEVELS]; };

// pack_hi(f0,f1): u32 = [f0.top16 | f1.top16<<16]  (bf16 by truncation) -- f0 low
__device__ __forceinline__ unsigned pack_hi(float f0, float f1) {
    return __builtin_amdgcn_perm(__float_as_uint(f1), __float_as_uint(f0), 0x07060302u);
}
// pack_lo(f0,f1): bf16(residuals) packed RTN, f0 low
__device__ __forceinline__ unsigned pack_lo(float f0, float f1) {
    const float l0 = f0 - __uint_as_float(__float_as_uint(f0) & 0xffff0000u);
    const float l1 = f1 - __uint_as_float(__float_as_uint(f1) & 0xffff0000u);
    unsigned r;
    asm("v_cvt_pk_bf16_f32 %0, %1, %2" : "=v"(r) : "v"(l0), "v"(l1));
    return r;
}

__device__ __forceinline__ unsigned bucket_of(float x, float y) {
    unsigned bx = (unsigned)(x * (float)BDIM); if (bx >= BDIM) bx = BDIM - 1;
    unsigned by = (unsigned)(y * (float)BDIM); if (by >= BDIM) by = BDIM - 1;
    unsigned m = 0;
    #pragma unroll
    for (int i = 0; i < 7; ++i)
        m |= (((bx >> i) & 1u) << (2 * i)) | (((by >> i) & 1u) << (2 * i + 1));
    return m;
}

// ONE cooperative kernel: hist -> scanw1 -> scanw2 -> top-scan -> scatter
// (+ wprep fused into block 0 phase 1). 256 blocks x 1024 thr, 64 KB LDS.
__global__ __launch_bounds__(STHR) void sort_coop(
    const float2* __restrict__ coords,
    unsigned* __restrict__ C32,
    unsigned* __restrict__ P,
    unsigned* __restrict__ T,
    unsigned* __restrict__ B,
    float2* __restrict__ sxy,
    unsigned* __restrict__ sidx,
    const float* __restrict__ W0,
    const float* __restrict__ W1,
    const float* __restrict__ W2,
    const float* __restrict__ b2,
    uint4* __restrict__ wbuf,
    float* __restrict__ b2p)
{
    cg::grid_group grid = cg::this_grid();
    __shared__ unsigned lds[NBUCK];          // 64 KB, reused across phases
    const int t = threadIdx.x;
    const int w = blockIdx.x;
    const int gid = w * STHR + t;            // 262144 global threads

    // ---- phase 1: per-block histogram (u8 packed 4/u32) ----
    #pragma unroll
    for (int i = t; i < NB4; i += STHR) lds[i] = 0u;
    __syncthreads();
    #pragma unroll
    for (int k = 0; k < SITER; ++k) {
        const int p = w * SPB + k * STHR + t;
        const float2 c = coords[p];
        const unsigned b = bucket_of(c.x, c.y);
        atomicAdd(&lds[b >> 2], 1u << ((b & 3u) * 8u));
    }
    __syncthreads();
    #pragma unroll
    for (int i = t; i < NB4; i += STHR)
        C32[(size_t)w * NB4 + i] = lds[i];

    // fused wprep (block 0, threads 0..383 — independent work)
    if (w == 0 && t < NFRAG) {
        const int fid  = t >> 6;
        const int lane = t & 63;
        const int l    = fid >> 1;
        const int kc   = fid & 1;
        const int l31  = lane & 31;
        const int hh   = lane >> 5;
        const float* Ws[3] = {W0, W1, W2};
        const int ncols[3] = {32, 32, 3};
        FragU H, L;
        #pragma unroll
        for (int e = 0; e < 8; ++e) {
            const int k = kc*16 + (e>>2)*8 + hh*4 + (e&3);
            const float wv = (l31 < ncols[l]) ? Ws[l][k*ncols[l] + l31] : 0.f;
            const unsigned short hi = (unsigned short)(__float_as_uint(wv) >> 16);
            const float rem = wv - __uint_as_float((unsigned)hi << 16);
            const unsigned u = __float_as_uint(rem);
            const unsigned short lo = (unsigned short)((u + 0x7fffu + ((u >> 16) & 1u)) >> 16);
            H.s[e] = hi;
            L.s[e] = lo;
        }
        wbuf[fid*64 + lane]         = H.q;
        wbuf[NFRAG + fid*64 + lane] = L.q;
        if (t < 32) b2p[t] = (t < 3) ? b2[t] : 0.f;
    }

    __threadfence();
    grid.sync();

    // ---- phase 2a: segmented byte-wise scan over WSEG=8 blocks ----
    if (gid < NSEG * NB4) {
        const int seg = gid >> 12;
        const int b4  = gid & (NB4 - 1);
        unsigned s0 = 0, s1 = 0, s2 = 0, s3 = 0;
        #pragma unroll
        for (int k = 0; k < WSEG; ++k) {
            const int ww = seg * WSEG + k;
            const size_t i = (size_t)ww * NB4 + b4;
            const unsigned u = C32[i];
            C32[i] = s0 | (s1 << 8) | (s2 << 16) | (s3 << 24);
            s0 += u & 255u;
            s1 += (u >> 8) & 255u;
            s2 += (u >> 16) & 255u;
            s3 += (u >> 24) & 255u;
        }
        const size_t pb = (size_t)seg * NBUCK + 4 * b4;
        P[pb + 0] = s0; P[pb + 1] = s1; P[pb + 2] = s2; P[pb + 3] = s3;
    }

    __threadfence();
    grid.sync();

    // ---- phase 2b: per-bucket scan over NSEG=32 segment totals ----
    if (gid < NBUCK) {
        unsigned s = 0;
        #pragma unroll
        for (int seg = 0; seg < NSEG; ++seg) {
            const size_t i = (size_t)seg * NBUCK + gid;
            const unsigned v = P[i];
            P[i] = s;
            s += v;
        }
        T[gid] = s;
    }

    __threadfence();
    grid.sync();

    // ---- phase 2c: top-level exclusive scan over T[16384] (block 0) ----
    if (w == 0) {
        unsigned loc[16];
        unsigned sum = 0;
        #pragma unroll
        for (int k = 0; k < 16; ++k) {
            const unsigned v = T[t * 16 + k];
            loc[k] = sum;
            sum += v;
        }
        lds[t] = sum;                        // reuse lds[0..1023]
        __syncthreads();
        for (int off = 1; off < STHR; off <<= 1) {
            const unsigned v = (t >= off) ? lds[t - off] : 0u;
            __syncthreads();
            lds[t] += v;
            __syncthreads();
        }
        const unsigned base = (t > 0) ? lds[t - 1] : 0u;
        #pragma unroll
        for (int k = 0; k < 16; ++k)
            B[t * 16 + k] = base + loc[k];
    }

    __threadfence();
    grid.sync();

    // ---- phase 3: scatter (LDS cursors over all 16384 buckets) ----
    const int seg = w / WSEG;
    #pragma unroll
    for (int i4 = t; i4 < NB4; i4 += STHR) {
        const unsigned wrd = C32[(size_t)w * NB4 + i4];
        #pragma unroll
        for (int j = 0; j < 4; ++j) {
            const int b = 4 * i4 + j;
            lds[b] = B[b] + P[(size_t)seg * NBUCK + b] + ((wrd >> (8 * j)) & 255u);
        }
    }
    __syncthreads();
    #pragma unroll
    for (int k = 0; k < SITER; ++k) {
        const int p = w * SPB + k * STHR + t;
        const float2 c = coords[p];
        const unsigned b = bucket_of(c.x, c.y);
        const unsigned pos = atomicAdd(&lds[b], 1u);
        sxy[pos] = c;
        sidx[pos] = (unsigned)p;
    }
}

__global__ __launch_bounds__(256, 4) void ngp_mfma(
    const float2* __restrict__ pts,      // sorted coords
    const unsigned* __restrict__ sidx,   // permutation
    const float* __restrict__ hashf,
    const uint4* __restrict__ wbuf,
    const float* __restrict__ b0,
    const float* __restrict__ b1,
    const float* __restrict__ b2p,
    float* __restrict__ out, ResArr res)
{
    // single staging buffer, reused hi-then-lo; wave-private rows -> no barriers
    __shared__ unsigned short X[256 * XSTRIDE];

    const unsigned nwg = gridDim.x;
    const unsigned chunk = nwg >> 3;
    const unsigned sb = (blockIdx.x & 7u) * chunk + (blockIdx.x >> 3);
    const int tid = threadIdx.x;
    const int p = (int)(sb * 256u) + tid;

    const float2 c = pts[p];

    // ---- interp: 4 software-pipelined chunks of 4 levels ----
    float f[32];
    float2 vA[16], vB[16];
    float2 wA[4], wB[4];

    auto issue = [&](int ck, float2* vv, float2* ww) {
        #pragma unroll
        for (int j = 0; j < 4; ++j) {
            const int r = ck * 4 + j;
            const float rr = res.r[r];
            const float x = c.x * rr;
            const float y = c.y * rr;
            const float xf = floorf(x);
            const float yf = floorf(y);
            ww[j].x = x - xf;
            ww[j].y = y - yf;
            const unsigned x0 = (unsigned)xf;
            const unsigned y0 = (unsigned)yf;
            const unsigned hy0 = PRIME_H * y0;
            const unsigned hy1 = PRIME_H * (y0 + 1u);
            const float2* tab = (const float2*)hashf + ((size_t)r << 19);
            vv[4*j+0] = tab[(x0 ^ hy0) & N_MASK];
            vv[4*j+1] = tab[(x0 ^ hy1) & N_MASK];
            vv[4*j+2] = tab[((x0 + 1u) ^ hy0) & N_MASK];
            vv[4*j+3] = tab[((x0 + 1u) ^ hy1) & N_MASK];
        }
    };
    auto consume = [&](int ck, const float2* vv, const float2* ww) {
        #pragma unroll
        for (int j = 0; j < 4; ++j) {
            const int r = ck * 4 + j;
            const float wx = ww[j].x, wy = ww[j].y;
            const float w00 = (1.f - wx) * (1.f - wy);
            const float w01 = (1.f - wx) * wy;
            const float w10 = wx * (1.f - wy);
            const float w11 = wx * wy;
            f[2*r+0] = vv[4*j+0].x*w00 + vv[4*j+1].x*w01 + vv[4*j+2].x*w10 + vv[4*j+3].x*w11;
            f[2*r+1] = vv[4*j+0].y*w00 + vv[4*j+1].y*w01 + vv[4*j+2].y*w10 + vv[4*j+3].y*w11;
        }
    };

    issue(0, vA, wA);
    issue(1, vB, wB);
    consume(0, vA, wA);
    issue(2, vA, wA);
    consume(1, vB, wB);
    issue(3, vB, wB);
    consume(2, vA, wA);
    consume(3, vB, wB);

    const int lane = tid & 63;
    const int wv   = tid >> 6;
    const int l31  = lane & 31;
    const int h    = lane >> 5;
    const int tb0  = wv * 64;
    const int tb1  = wv * 64 + 32;
    const int rowo = tid * XSTRIDE;

    auto ldx = [&](int ptl, int kc) -> FragU {
        FragU r;
        const int off = ptl * XSTRIDE + kc * 16 + h * 4;
        r.u2[0] = *(const uint2*)&X[off];
        r.u2[1] = *(const uint2*)&X[off + 8];
        return r;
    };

    // ---- pass 1: stage hi, read hi fragments ----
    #pragma unroll
    for (int q = 0; q < 8; ++q) {
        uint2 ph;
        ph.x = pack_hi(f[4*q+0], f[4*q+1]);
        ph.y = pack_hi(f[4*q+2], f[4*q+3]);
        *(uint2*)&X[rowo + 4*q] = ph;
    }
    FragU Ah0 = ldx(tb0 + l31, 0);
    FragU Ah1 = ldx(tb0 + l31, 1);
    FragU Bh0 = ldx(tb1 + l31, 0);
    FragU Bh1 = ldx(tb1 + l31, 1);

    // ---- pass 2: stage lo (same rows), read lo fragments ----
    #pragma unroll
    for (int q = 0; q < 8; ++q) {
        uint2 pl;
        pl.x = pack_lo(f[4*q+0], f[4*q+1]);
        pl.y = pack_lo(f[4*q+2], f[4*q+3]);
        *(uint2*)&X[rowo + 4*q] = pl;
    }
    FragU Al0 = ldx(tb0 + l31, 0);
    FragU Al1 = ldx(tb0 + l31, 1);
    FragU Bl0 = ldx(tb1 + l31, 0);
    FragU Bl1 = ldx(tb1 + l31, 1);

    // a[4q+j] = b[8q + 4h + j]
    auto bias_init = [&](const float* b) -> f32x16 {
        f32x16 a;
        #pragma unroll
        for (int q = 0; q < 4; ++q) {
            const float4 t = *(const float4*)(b + 8*q + 4*h);
            a[4*q+0] = t.x; a[4*q+1] = t.y; a[4*q+2] = t.z; a[4*q+3] = t.w;
        }
        return a;
    };

    f32x16 a0, a1;

    auto layer = [&](int l, const float* b) {
        FragU wh0, wl0, wh1, wl1;
        wh0.q = wbuf[(l*2+0)*64 + lane];
        wl0.q = wbuf[NFRAG + (l*2+0)*64 + lane];
        wh1.q = wbuf[(l*2+1)*64 + lane];
        wl1.q = wbuf[NFRAG + (l*2+1)*64 + lane];
        f32x16 A0 = bias_init(b);
        f32x16 A1 = A0;
        A0 = __builtin_amdgcn_mfma_f32_32x32x16_bf16(wh0.v, Ah0.v, A0, 0, 0, 0);
        A0 = __builtin_amdgcn_mfma_f32_32x32x16_bf16(wh0.v, Al0.v, A0, 0, 0, 0);
        A0 = __builtin_amdgcn_mfma_f32_32x32x16_bf16(wl0.v, Ah0.v, A0, 0, 0, 0);
        A0 = __builtin_amdgcn_mfma_f32_32x32x16_bf16(wh1.v, Ah1.v, A0, 0, 0, 0);
        A0 = __builtin_amdgcn_mfma_f32_32x32x16_bf16(wh1.v, Al1.v, A0, 0, 0, 0);
        A0 = __builtin_amdgcn_mfma_f32_32x32x16_bf16(wl1.v, Ah1.v, A0, 0, 0, 0);
        A1 = __builtin_amdgcn_mfma_f32_32x32x16_bf16(wh0.v, Bh0.v, A1, 0, 0, 0);
        A1 = __builtin_amdgcn_mfma_f32_32x32x16_bf16(wh0.v, Bl0.v, A1, 0, 0, 0);
        A1 = __builtin_amdgcn_mfma_f32_32x32x16_bf16(wl0.v, Bh0.v, A1, 0, 0, 0);
        A1 = __builtin_amdgcn_mfma_f32_32x32x16_bf16(wh1.v, Bh1.v, A1, 0, 0, 0);
        A1 = __builtin_amdgcn_mfma_f32_32x32x16_bf16(wh1.v, Bl1.v, A1, 0, 0, 0);
        A1 = __builtin_amdgcn_mfma_f32_32x32x16_bf16(wl1.v, Bh1.v, A1, 0, 0, 0);
        a0 = A0; a1 = A1;
    };

    // leaky + hi/lo repack in-register: D reg e -> kc0 frag elem e; reg 8+e -> kc1 elem e
    auto act_repack = [&](const f32x16& a, FragU& xh0, FragU& xl0, FragU& xh1, FragU& xl1) {
        float v[16];
        #pragma unroll
        for (int r = 0; r < 16; ++r) v[r] = fmaxf(a[r], 0.01f * a[r]);
        #pragma unroll
        for (int w = 0; w < 4; ++w) {
            xh0.u[w] = pack_hi(v[2*w],   v[2*w+1]);
            xl0.u[w] = pack_lo(v[2*w],   v[2*w+1]);
            xh1.u[w] = pack_hi(v[8+2*w], v[8+2*w+1]);
            xl1.u[w] = pack_lo(v[8+2*w], v[8+2*w+1]);
        }
    };

    layer(0, b0);
    act_repack(a0, Ah0, Al0, Ah1, Al1);
    act_repack(a1, Bh0, Bl0, Bh1, Bl1);
    layer(1, b1);
    act_repack(a0, Ah0, Al0, Ah1, Al1);
    act_repack(a1, Bh0, Bl0, Bh1, Bl1);
    layer(2, b2p);

    if (h == 0) {
        const int pl0 = (int)(sb * 256u) + tb0 + l31;
        const int pl1 = (int)(sb * 256u) + tb1 + l31;
        const unsigned o0 = sidx ? sidx[pl0] : (unsigned)pl0;
        const unsigned o1 = sidx ? sidx[pl1] : (unsigned)pl1;
        out[(size_t)o0*3 + 0] = a0[0];
        out[(size_t)o0*3 + 1] = a0[1];
        out[(size_t)o0*3 + 2] = a0[2];
        out[(size_t)o1*3 + 0] = a1[0];
        out[(size_t)o1*3 + 1] = a1[1];
        out[(size_t)o1*3 + 2] = a1[2];
    }
}

extern "C" void kernel_launch(void* const* d_in, const int* in_sizes, int n_in,
                              void* d_out, int out_size, void* d_ws, size_t ws_size,
                              hipStream_t stream) {
    ResArr res;
    for (int i = 0; i < R_LEVELS; ++i)
        res.r[i] = (float)nearbyint(exp2(4.0 + (7.0 / 15.0) * (double)i));
    res.r[0] = 16.f;
    res.r[R_LEVELS - 1] = 2048.f;

    const float2* coords = (const float2*)d_in[0];
    const float* hashf   = (const float*)d_in[1];
    const float* W0      = (const float*)d_in[2];
    const float* b0      = (const float*)d_in[3];
    const float* W1      = (const float*)d_in[4];
    const float* b1      = (const float*)d_in[5];
    const float* W2      = (const float*)d_in[6];
    const float* b2      = (const float*)d_in[7];
    float* out           = (float*)d_out;

    // ws: C32 u32[256*4096] | P u32[32*16384] | T | B | sxy f2[M] | sidx u32[M] | wbuf | b2p
    const size_t off_C    = 0;
    const size_t off_P    = off_C + (size_t)SBLK * NB4 * 4;         // 4 MB
    const size_t off_T    = off_P + (size_t)NSEG * NBUCK * 4;       // +2 MB
    const size_t off_B    = off_T + NBUCK * 4;
    const size_t off_sxy  = off_B + NBUCK * 4;
    const size_t off_sidx = off_sxy + (size_t)M_PTS * sizeof(float2);
    const size_t off_wbuf = off_sidx + (size_t)M_PTS * 4;
    const size_t off_b2p  = off_wbuf + 2 * NFRAG * sizeof(uint4);
    const size_t need     = off_b2p + 32 * sizeof(float);

    dim3 blockM(256);
    dim3 gridM(M_PTS / 256);

    if (ws_size >= need) {
        unsigned* C32  = (unsigned*)((char*)d_ws + off_C);
        unsigned* P    = (unsigned*)((char*)d_ws + off_P);
        unsigned* T    = (unsigned*)((char*)d_ws + off_T);
        unsigned* B    = (unsigned*)((char*)d_ws + off_B);
        float2*   sxy  = (float2*)((char*)d_ws + off_sxy);
        unsigned* sidx = (unsigned*)((char*)d_ws + off_sidx);
        uint4*    wbuf = (uint4*)((char*)d_ws + off_wbuf);
        float*    b2p  = (float*)((char*)d_ws + off_b2p);

        void* args[] = {
            (void*)&coords, (void*)&C32, (void*)&P, (void*)&T, (void*)&B,
            (void*)&sxy, (void*)&sidx,
            (void*)&W0, (void*)&W1, (void*)&W2, (void*)&b2,
            (void*)&wbuf, (void*)&b2p
        };
        hipLaunchCooperativeKernel((const void*)sort_coop, dim3(SBLK), dim3(STHR),
                                   args, 0, stream);
        hipLaunchKernelGGL(ngp_mfma, gridM, blockM, 0, stream,
                           sxy, sidx, hashf, wbuf, b0, b1, b2p, out, res);
    }
}

// Round 16
// 196.456 us; speedup vs baseline: 2.7487x; 2.7487x over previous
//
#include <hip/hip_runtime.h>
#include <cmath>

#define R_LEVELS 16
#define N_TAB    524288u
#define N_MASK   (N_TAB - 1u)
#define PRIME_H  2654435761u
#define M_PTS    1048576
#define BDIM     128              // buckets per axis
#define NBUCK    (BDIM * BDIM)    // 16384 Morton buckets
#define NB4      (NBUCK / 4)      // packed u32 groups = 4096
#define SBLK     256              // sort blocks (whole chip)
#define STHR     1024
#define SPB      (M_PTS / SBLK)   // 4096
#define SITER    (SPB / STHR)     // 4
#define XSTRIDE  36               // bf16 elems per LDS row: 32 ch + 4 pad (72 B)
#define NFRAG    384              // 6 (layer,kc) x 64 lanes

typedef __attribute__((ext_vector_type(8)))  short bf16x8;
typedef __attribute__((ext_vector_type(16))) float f32x16;

union FragU { bf16x8 v; uint4 q; unsigned u[4]; uint2 u2[2]; unsigned short s[8]; };

struct ResArr { float r[R_LEVELS]; };

// pack_hi(f0,f1): u32 = [f0.top16 | f1.top16<<16]  (bf16 by truncation) -- f0 low
__device__ __forceinline__ unsigned pack_hi(float f0, float f1) {
    return __builtin_amdgcn_perm(__float_as_uint(f1), __float_as_uint(f0), 0x07060302u);
}
// pack_lo(f0,f1): bf16(residuals) packed RTN, f0 low
__device__ __forceinline__ unsigned pack_lo(float f0, float f1) {
    const float l0 = f0 - __uint_as_float(__float_as_uint(f0) & 0xffff0000u);
    const float l1 = f1 - __uint_as_float(__float_as_uint(f1) & 0xffff0000u);
    unsigned r;
    asm("v_cvt_pk_bf16_f32 %0, %1, %2" : "=v"(r) : "v"(l0), "v"(l1));
    return r;
}

__device__ __forceinline__ unsigned bucket_of(float x, float y) {
    unsigned bx = (unsigned)(x * (float)BDIM); if (bx >= BDIM) bx = BDIM - 1;
    unsigned by = (unsigned)(y * (float)BDIM); if (by >= BDIM) by = BDIM - 1;
    unsigned m = 0;
    #pragma unroll
    for (int i = 0; i < 7; ++i)
        m |= (((bx >> i) & 1u) << (2 * i)) | (((by >> i) & 1u) << (2 * i + 1));
    return m;
}

// Pass 1: per-block LDS histogram (u8 packed), then SPARSE atomic add of
// nonzero counts into global T[16384]. Block 0 also precomputes W fragments.
__global__ __launch_bounds__(STHR) void hist_k(const float2* __restrict__ coords,
                                               unsigned* __restrict__ T,
                                               const float* __restrict__ W0,
                                               const float* __restrict__ W1,
                                               const float* __restrict__ W2,
                                               const float* __restrict__ b2,
                                               uint4* __restrict__ wbuf,
                                               float* __restrict__ b2p) {
    __shared__ unsigned h[NB4];     // 16 KB
    const int t = threadIdx.x;
    const int w = blockIdx.x;
    #pragma unroll
    for (int i = t; i < NB4; i += STHR) h[i] = 0u;
    __syncthreads();
    #pragma unroll
    for (int k = 0; k < SITER; ++k) {
        const int p = w * SPB + k * STHR + t;
        const float2 c = coords[p];
        const unsigned b = bucket_of(c.x, c.y);
        atomicAdd(&h[b >> 2], 1u << ((b & 3u) * 8u));
    }
    __syncthreads();
    #pragma unroll
    for (int i4 = t; i4 < NB4; i4 += STHR) {
        const unsigned wrd = h[i4];
        if (wrd) {
            #pragma unroll
            for (int j = 0; j < 4; ++j) {
                const unsigned cnt = (wrd >> (8 * j)) & 255u;
                if (cnt) atomicAdd(&T[4 * i4 + j], cnt);
            }
        }
    }

    // ---- fused wprep: block 0, threads 0..383 ----
    if (w == 0 && t < NFRAG) {
        const int fid  = t >> 6;          // 0..5 = l*2+kc
        const int lane = t & 63;
        const int l    = fid >> 1;
        const int kc   = fid & 1;
        const int l31  = lane & 31;
        const int hh   = lane >> 5;
        const float* Ws[3] = {W0, W1, W2};
        const int ncols[3] = {32, 32, 3};
        FragU H, L;
        #pragma unroll
        for (int e = 0; e < 8; ++e) {
            const int k = kc*16 + (e>>2)*8 + hh*4 + (e&3);
            const float wv = (l31 < ncols[l]) ? Ws[l][k*ncols[l] + l31] : 0.f;
            const unsigned short hi = (unsigned short)(__float_as_uint(wv) >> 16);
            const float rem = wv - __uint_as_float((unsigned)hi << 16);
            const unsigned u = __float_as_uint(rem);
            const unsigned short lo = (unsigned short)((u + 0x7fffu + ((u >> 16) & 1u)) >> 16);
            H.s[e] = hi;
            L.s[e] = lo;
        }
        wbuf[fid*64 + lane]         = H.q;
        wbuf[NFRAG + fid*64 + lane] = L.q;
        if (t < 32) b2p[t] = (t < 3) ? b2[t] : 0.f;
    }
}

// Pass 2: exclusive prefix over T[16384] -> B (single block, 1024 thr, 16/thread)
__global__ __launch_bounds__(1024) void scan_k(const unsigned* __restrict__ T,
                                               unsigned* __restrict__ B) {
    __shared__ unsigned part[1024];
    const int t = threadIdx.x;
    unsigned loc[16];
    unsigned sum = 0;
    #pragma unroll
    for (int k = 0; k < 16; ++k) {
        const unsigned v = T[t * 16 + k];
        loc[k] = sum;
        sum += v;
    }
    part[t] = sum;
    __syncthreads();
    for (int off = 1; off < 1024; off <<= 1) {
        const unsigned v = (t >= off) ? part[t - off] : 0u;
        __syncthreads();
        part[t] += v;
        __syncthreads();
    }
    const unsigned base = (t > 0) ? part[t - 1] : 0u;
    #pragma unroll
    for (int k = 0; k < 16; ++k)
        B[t * 16 + k] = base + loc[k];
}

// Pass 3: scatter via global bucket cursors (B mutated in place).
// Within-bucket order is nondeterministic but per-point output values are
// order-independent, so final d_out stays deterministic.
__global__ __launch_bounds__(STHR) void scatter_k(const float2* __restrict__ coords,
                                                  unsigned* __restrict__ B,
                                                  float2* __restrict__ sxy,
                                                  unsigned* __restrict__ sidx) {
    const int t = threadIdx.x;
    const int w = blockIdx.x;
    #pragma unroll
    for (int k = 0; k < SITER; ++k) {
        const int p = w * SPB + k * STHR + t;
        const float2 c = coords[p];
        const unsigned b = bucket_of(c.x, c.y);
        const unsigned pos = atomicAdd(&B[b], 1u);
        sxy[pos] = c;
        sidx[pos] = (unsigned)p;
    }
}

__global__ __launch_bounds__(256, 4) void ngp_mfma(
    const float2* __restrict__ pts,      // sorted coords
    const unsigned* __restrict__ sidx,   // permutation
    const float* __restrict__ hashf,
    const uint4* __restrict__ wbuf,
    const float* __restrict__ b0,
    const float* __restrict__ b1,
    const float* __restrict__ b2p,
    float* __restrict__ out, ResArr res)
{
    // single staging buffer, reused hi-then-lo; wave-private rows -> no barriers
    __shared__ unsigned short X[256 * XSTRIDE];

    const unsigned nwg = gridDim.x;
    const unsigned chunk = nwg >> 3;
    const unsigned sb = (blockIdx.x & 7u) * chunk + (blockIdx.x >> 3);
    const int tid = threadIdx.x;
    const int p = (int)(sb * 256u) + tid;

    const float2 c = pts[p];

    // ---- interp: 4 software-pipelined chunks of 4 levels ----
    float f[32];
    float2 vA[16], vB[16];
    float2 wA[4], wB[4];

    auto issue = [&](int ck, float2* vv, float2* ww) {
        #pragma unroll
        for (int j = 0; j < 4; ++j) {
            const int r = ck * 4 + j;
            const float rr = res.r[r];
            const float x = c.x * rr;
            const float y = c.y * rr;
            const float xf = floorf(x);
            const float yf = floorf(y);
            ww[j].x = x - xf;
            ww[j].y = y - yf;
            const unsigned x0 = (unsigned)xf;
            const unsigned y0 = (unsigned)yf;
            const unsigned hy0 = PRIME_H * y0;
            const unsigned hy1 = PRIME_H * (y0 + 1u);
            const float2* tab = (const float2*)hashf + ((size_t)r << 19);
            vv[4*j+0] = tab[(x0 ^ hy0) & N_MASK];
            vv[4*j+1] = tab[(x0 ^ hy1) & N_MASK];
            vv[4*j+2] = tab[((x0 + 1u) ^ hy0) & N_MASK];
            vv[4*j+3] = tab[((x0 + 1u) ^ hy1) & N_MASK];
        }
    };
    auto consume = [&](int ck, const float2* vv, const float2* ww) {
        #pragma unroll
        for (int j = 0; j < 4; ++j) {
            const int r = ck * 4 + j;
            const float wx = ww[j].x, wy = ww[j].y;
            const float w00 = (1.f - wx) * (1.f - wy);
            const float w01 = (1.f - wx) * wy;
            const float w10 = wx * (1.f - wy);
            const float w11 = wx * wy;
            f[2*r+0] = vv[4*j+0].x*w00 + vv[4*j+1].x*w01 + vv[4*j+2].x*w10 + vv[4*j+3].x*w11;
            f[2*r+1] = vv[4*j+0].y*w00 + vv[4*j+1].y*w01 + vv[4*j+2].y*w10 + vv[4*j+3].y*w11;
        }
    };

    issue(0, vA, wA);
    issue(1, vB, wB);
    consume(0, vA, wA);
    issue(2, vA, wA);
    consume(1, vB, wB);
    issue(3, vB, wB);
    consume(2, vA, wA);
    consume(3, vB, wB);

    const int lane = tid & 63;
    const int wv   = tid >> 6;
    const int l31  = lane & 31;
    const int h    = lane >> 5;
    const int tb0  = wv * 64;
    const int tb1  = wv * 64 + 32;
    const int rowo = tid * XSTRIDE;

    auto ldx = [&](int ptl, int kc) -> FragU {
        FragU r;
        const int off = ptl * XSTRIDE + kc * 16 + h * 4;
        r.u2[0] = *(const uint2*)&X[off];
        r.u2[1] = *(const uint2*)&X[off + 8];
        return r;
    };

    // ---- pass 1: stage hi, read hi fragments ----
    #pragma unroll
    for (int q = 0; q < 8; ++q) {
        uint2 ph;
        ph.x = pack_hi(f[4*q+0], f[4*q+1]);
        ph.y = pack_hi(f[4*q+2], f[4*q+3]);
        *(uint2*)&X[rowo + 4*q] = ph;
    }
    FragU Ah0 = ldx(tb0 + l31, 0);
    FragU Ah1 = ldx(tb0 + l31, 1);
    FragU Bh0 = ldx(tb1 + l31, 0);
    FragU Bh1 = ldx(tb1 + l31, 1);

    // ---- pass 2: stage lo (same rows), read lo fragments ----
    #pragma unroll
    for (int q = 0; q < 8; ++q) {
        uint2 pl;
        pl.x = pack_lo(f[4*q+0], f[4*q+1]);
        pl.y = pack_lo(f[4*q+2], f[4*q+3]);
        *(uint2*)&X[rowo + 4*q] = pl;
    }
    FragU Al0 = ldx(tb0 + l31, 0);
    FragU Al1 = ldx(tb0 + l31, 1);
    FragU Bl0 = ldx(tb1 + l31, 0);
    FragU Bl1 = ldx(tb1 + l31, 1);

    // a[4q+j] = b[8q + 4h + j]
    auto bias_init = [&](const float* b) -> f32x16 {
        f32x16 a;
        #pragma unroll
        for (int q = 0; q < 4; ++q) {
            const float4 t = *(const float4*)(b + 8*q + 4*h);
            a[4*q+0] = t.x; a[4*q+1] = t.y; a[4*q+2] = t.z; a[4*q+3] = t.w;
        }
        return a;
    };

    f32x16 a0, a1;

    auto layer = [&](int l, const float* b) {
        FragU wh0, wl0, wh1, wl1;
        wh0.q = wbuf[(l*2+0)*64 + lane];
        wl0.q = wbuf[NFRAG + (l*2+0)*64 + lane];
        wh1.q = wbuf[(l*2+1)*64 + lane];
        wl1.q = wbuf[NFRAG + (l*2+1)*64 + lane];
        f32x16 A0 = bias_init(b);
        f32x16 A1 = A0;
        A0 = __builtin_amdgcn_mfma_f32_32x32x16_bf16(wh0.v, Ah0.v, A0, 0, 0, 0);
        A0 = __builtin_amdgcn_mfma_f32_32x32x16_bf16(wh0.v, Al0.v, A0, 0, 0, 0);
        A0 = __builtin_amdgcn_mfma_f32_32x32x16_bf16(wl0.v, Ah0.v, A0, 0, 0, 0);
        A0 = __builtin_amdgcn_mfma_f32_32x32x16_bf16(wh1.v, Ah1.v, A0, 0, 0, 0);
        A0 = __builtin_amdgcn_mfma_f32_32x32x16_bf16(wh1.v, Al1.v, A0, 0, 0, 0);
        A0 = __builtin_amdgcn_mfma_f32_32x32x16_bf16(wl1.v, Ah1.v, A0, 0, 0, 0);
        A1 = __builtin_amdgcn_mfma_f32_32x32x16_bf16(wh0.v, Bh0.v, A1, 0, 0, 0);
        A1 = __builtin_amdgcn_mfma_f32_32x32x16_bf16(wh0.v, Bl0.v, A1, 0, 0, 0);
        A1 = __builtin_amdgcn_mfma_f32_32x32x16_bf16(wl0.v, Bh0.v, A1, 0, 0, 0);
        A1 = __builtin_amdgcn_mfma_f32_32x32x16_bf16(wh1.v, Bh1.v, A1, 0, 0, 0);
        A1 = __builtin_amdgcn_mfma_f32_32x32x16_bf16(wh1.v, Bl1.v, A1, 0, 0, 0);
        A1 = __builtin_amdgcn_mfma_f32_32x32x16_bf16(wl1.v, Bh1.v, A1, 0, 0, 0);
        a0 = A0; a1 = A1;
    };

    // leaky + hi/lo repack in-register: D reg e -> kc0 frag elem e; reg 8+e -> kc1 elem e
    auto act_repack = [&](const f32x16& a, FragU& xh0, FragU& xl0, FragU& xh1, FragU& xl1) {
        float v[16];
        #pragma unroll
        for (int r = 0; r < 16; ++r) v[r] = fmaxf(a[r], 0.01f * a[r]);
        #pragma unroll
        for (int w = 0; w < 4; ++w) {
            xh0.u[w] = pack_hi(v[2*w],   v[2*w+1]);
            xl0.u[w] = pack_lo(v[2*w],   v[2*w+1]);
            xh1.u[w] = pack_hi(v[8+2*w], v[8+2*w+1]);
            xl1.u[w] = pack_lo(v[8+2*w], v[8+2*w+1]);
        }
    };

    layer(0, b0);
    act_repack(a0, Ah0, Al0, Ah1, Al1);
    act_repack(a1, Bh0, Bl0, Bh1, Bl1);
    layer(1, b1);
    act_repack(a0, Ah0, Al0, Ah1, Al1);
    act_repack(a1, Bh0, Bl0, Bh1, Bl1);
    layer(2, b2p);

    if (h == 0) {
        const int pl0 = (int)(sb * 256u) + tb0 + l31;
        const int pl1 = (int)(sb * 256u) + tb1 + l31;
        const unsigned o0 = sidx[pl0];
        const unsigned o1 = sidx[pl1];
        out[(size_t)o0*3 + 0] = a0[0];
        out[(size_t)o0*3 + 1] = a0[1];
        out[(size_t)o0*3 + 2] = a0[2];
        out[(size_t)o1*3 + 0] = a1[0];
        out[(size_t)o1*3 + 1] = a1[1];
        out[(size_t)o1*3 + 2] = a1[2];
    }
}

extern "C" void kernel_launch(void* const* d_in, const int* in_sizes, int n_in,
                              void* d_out, int out_size, void* d_ws, size_t ws_size,
                              hipStream_t stream) {
    ResArr res;
    for (int i = 0; i < R_LEVELS; ++i)
        res.r[i] = (float)nearbyint(exp2(4.0 + (7.0 / 15.0) * (double)i));
    res.r[0] = 16.f;
    res.r[R_LEVELS - 1] = 2048.f;

    const float2* coords = (const float2*)d_in[0];
    const float* hashf   = (const float*)d_in[1];
    const float* W0      = (const float*)d_in[2];
    const float* b0      = (const float*)d_in[3];
    const float* W1      = (const float*)d_in[4];
    const float* b1      = (const float*)d_in[5];
    const float* W2      = (const float*)d_in[6];
    const float* b2      = (const float*)d_in[7];
    float* out           = (float*)d_out;

    // ws: T u32[16384] | B u32[16384] | sxy f2[M] | sidx u32[M] | wbuf | b2p
    const size_t off_T    = 0;
    const size_t off_B    = off_T + NBUCK * 4;
    const size_t off_sxy  = off_B + NBUCK * 4;
    const size_t off_sidx = off_sxy + (size_t)M_PTS * sizeof(float2);
    const size_t off_wbuf = off_sidx + (size_t)M_PTS * 4;
    const size_t off_b2p  = off_wbuf + 2 * NFRAG * sizeof(uint4);
    const size_t need     = off_b2p + 32 * sizeof(float);

    dim3 blockM(256);
    dim3 gridM(M_PTS / 256);

    if (ws_size >= need) {
        unsigned* T    = (unsigned*)((char*)d_ws + off_T);
        unsigned* B    = (unsigned*)((char*)d_ws + off_B);
        float2*   sxy  = (float2*)((char*)d_ws + off_sxy);
        unsigned* sidx = (unsigned*)((char*)d_ws + off_sidx);
        uint4*    wbuf = (uint4*)((char*)d_ws + off_wbuf);
        float*    b2p  = (float*)((char*)d_ws + off_b2p);

        hipMemsetAsync(T, 0, NBUCK * 4, stream);
        hipLaunchKernelGGL(hist_k,    dim3(SBLK), dim3(STHR), 0, stream,
                           coords, T, W0, W1, W2, b2, wbuf, b2p);
        hipLaunchKernelGGL(scan_k,    dim3(1), dim3(1024), 0, stream, T, B);
        hipLaunchKernelGGL(scatter_k, dim3(SBLK), dim3(STHR), 0, stream,
                           coords, B, sxy, sidx);
        hipLaunchKernelGGL(ngp_mfma,  gridM, blockM, 0, stream,
                           sxy, sidx, hashf, wbuf, b0, b1, b2p, out, res);
    }
}

// Round 17
// 106.061 us; speedup vs baseline: 5.0914x; 1.8523x over previous
//
#include <hip/hip_runtime.h>
#include <cmath>

#define R_LEVELS 16
#define N_TAB    524288u
#define N_MASK   (N_TAB - 1u)
#define PRIME_H  2654435761u
#define M_PTS    1048576
#define BDIM     128              // buckets per axis
#define NBUCK    (BDIM * BDIM)    // 16384 Morton buckets
#define NB4      (NBUCK / 4)      // packed u32 groups = 4096
#define SBLK     256              // sort blocks (whole chip)
#define STHR     1024
#define SPB      (M_PTS / SBLK)   // 4096
#define SITER    (SPB / STHR)     // 4
#define NSEG     8                // scanw segments
#define WSEG     (SBLK / NSEG)    // 32 blocks per segment
#define XSTRIDE  36               // bf16 elems per LDS row: 32 ch + 4 pad (72 B)
#define NFRAG    384              // 6 (layer,kc) x 64 lanes

typedef __attribute__((ext_vector_type(8)))  short bf16x8;
typedef __attribute__((ext_vector_type(16))) float f32x16;

union FragU { bf16x8 v; uint4 q; unsigned u[4]; uint2 u2[2]; unsigned short s[8]; };

struct ResArr { float r[R_LEVELS]; };

// pack_hi(f0,f1): u32 = [f0.top16 | f1.top16<<16]  (bf16 by truncation) -- f0 low
__device__ __forceinline__ unsigned pack_hi(float f0, float f1) {
    return __builtin_amdgcn_perm(__float_as_uint(f1), __float_as_uint(f0), 0x07060302u);
}
// pack_lo(f0,f1): bf16(residuals) packed RTN, f0 low
__device__ __forceinline__ unsigned pack_lo(float f0, float f1) {
    const float l0 = f0 - __uint_as_float(__float_as_uint(f0) & 0xffff0000u);
    const float l1 = f1 - __uint_as_float(__float_as_uint(f1) & 0xffff0000u);
    unsigned r;
    asm("v_cvt_pk_bf16_f32 %0, %1, %2" : "=v"(r) : "v"(l0), "v"(l1));
    return r;
}

__device__ __forceinline__ unsigned bucket_of(float x, float y) {
    unsigned bx = (unsigned)(x * (float)BDIM); if (bx >= BDIM) bx = BDIM - 1;
    unsigned by = (unsigned)(y * (float)BDIM); if (by >= BDIM) by = BDIM - 1;
    unsigned m = 0;
    #pragma unroll
    for (int i = 0; i < 7; ++i)
        m |= (((bx >> i) & 1u) << (2 * i)) | (((by >> i) & 1u) << (2 * i + 1));
    return m;
}

// Pass 1: per-block LDS histogram, u8 counts packed 4/u32 -> C32[block][NB4]
// Block 0 additionally precomputes weight fragments (independent tail work).
__global__ __launch_bounds__(STHR) void hist_k(const float2* __restrict__ coords,
                                               unsigned* __restrict__ C32,
                                               const float* __restrict__ W0,
                                               const float* __restrict__ W1,
                                               const float* __restrict__ W2,
                                               const float* __restrict__ b2,
                                               uint4* __restrict__ wbuf,
                                               float* __restrict__ b2p) {
    __shared__ unsigned h[NB4];     // 16 KB
    const int t = threadIdx.x;
    const int w = blockIdx.x;
    #pragma unroll
    for (int i = t; i < NB4; i += STHR) h[i] = 0u;
    __syncthreads();
    #pragma unroll
    for (int k = 0; k < SITER; ++k) {
        const int p = w * SPB + k * STHR + t;
        const float2 c = coords[p];
        const unsigned b = bucket_of(c.x, c.y);
        atomicAdd(&h[b >> 2], 1u << ((b & 3u) * 8u));
    }
    __syncthreads();
    #pragma unroll
    for (int i = t; i < NB4; i += STHR)
        C32[(size_t)w * NB4 + i] = h[i];

    // ---- fused wprep: block 0, threads 0..383 ----
    if (w == 0 && t < NFRAG) {
        const int fid  = t >> 6;          // 0..5 = l*2+kc
        const int lane = t & 63;
        const int l    = fid >> 1;
        const int kc   = fid & 1;
        const int l31  = lane & 31;
        const int hh   = lane >> 5;
        const float* Ws[3] = {W0, W1, W2};
        const int ncols[3] = {32, 32, 3};
        FragU H, L;
        #pragma unroll
        for (int e = 0; e < 8; ++e) {
            const int k = kc*16 + (e>>2)*8 + hh*4 + (e&3);
            const float wv = (l31 < ncols[l]) ? Ws[l][k*ncols[l] + l31] : 0.f;
            const unsigned short hi = (unsigned short)(__float_as_uint(wv) >> 16);
            const float rem = wv - __uint_as_float((unsigned)hi << 16);
            const unsigned u = __float_as_uint(rem);
            const unsigned short lo = (unsigned short)((u + 0x7fffu + ((u >> 16) & 1u)) >> 16);
            H.s[e] = hi;
            L.s[e] = lo;
        }
        wbuf[fid*64 + lane]         = H.q;
        wbuf[NFRAG + fid*64 + lane] = L.q;
        if (t < 32) b2p[t] = (t < 3) ? b2[t] : 0.f;
    }
}

// Standalone wprep (fallback path only)
__global__ __launch_bounds__(384) void wprep_k(const float* __restrict__ W0,
                                               const float* __restrict__ W1,
                                               const float* __restrict__ W2,
                                               const float* __restrict__ b2,
                                               uint4* __restrict__ wbuf,
                                               float* __restrict__ b2p) {
    const int t    = threadIdx.x;
    const int fid  = t >> 6;
    const int lane = t & 63;
    const int l    = fid >> 1;
    const int kc   = fid & 1;
    const int l31  = lane & 31;
    const int h    = lane >> 5;
    const float* Ws[3] = {W0, W1, W2};
    const int ncols[3] = {32, 32, 3};
    FragU H, L;
    #pragma unroll
    for (int e = 0; e < 8; ++e) {
        const int k = kc*16 + (e>>2)*8 + h*4 + (e&3);
        const float w = (l31 < ncols[l]) ? Ws[l][k*ncols[l] + l31] : 0.f;
        const unsigned short hi = (unsigned short)(__float_as_uint(w) >> 16);
        const float rem = w - __uint_as_float((unsigned)hi << 16);
        const unsigned u = __float_as_uint(rem);
        const unsigned short lo = (unsigned short)((u + 0x7fffu + ((u >> 16) & 1u)) >> 16);
        H.s[e] = hi;
        L.s[e] = lo;
    }
    wbuf[fid*64 + lane]         = H.q;
    wbuf[NFRAG + fid*64 + lane] = L.q;
    if (t < 32) b2p[t] = (t < 3) ? b2[t] : 0.f;
}

// Pass 2a (segmented, byte-wise): per (seg, u32-group): prefix over WSEG=32 blocks.
__global__ __launch_bounds__(256) void scanw1_k(unsigned* __restrict__ C32,
                                                unsigned* __restrict__ P) {
    const int g = blockIdx.x * 256 + threadIdx.x;   // NSEG*NB4 = 32768 threads
    const int seg = g >> 12;
    const int b4  = g & (NB4 - 1);
    unsigned s0 = 0, s1 = 0, s2 = 0, s3 = 0;
    #pragma unroll
    for (int k = 0; k < WSEG; ++k) {
        const int w = seg * WSEG + k;
        const size_t i = (size_t)w * NB4 + b4;
        const unsigned u = C32[i];
        C32[i] = s0 | (s1 << 8) | (s2 << 16) | (s3 << 24);
        s0 += u & 255u;
        s1 += (u >> 8) & 255u;
        s2 += (u >> 16) & 255u;
        s3 += (u >> 24) & 255u;
    }
    const size_t pb = (size_t)seg * NBUCK + 4 * b4;
    P[pb + 0] = s0; P[pb + 1] = s1; P[pb + 2] = s2; P[pb + 3] = s3;
}

// Pass 2b: per bucket: prefix over NSEG=8 segment totals; T[b] <- bucket total.
__global__ __launch_bounds__(256) void scanw2_k(unsigned* __restrict__ P,
                                                unsigned* __restrict__ T) {
    const int b = blockIdx.x * 256 + threadIdx.x;   // 16384 threads
    unsigned s = 0;
    #pragma unroll
    for (int seg = 0; seg < NSEG; ++seg) {
        const size_t i = (size_t)seg * NBUCK + b;
        const unsigned v = P[i];
        P[i] = s;
        s += v;
    }
    T[b] = s;
}

// Pass 2c: exclusive prefix over T[16384] (single block, 64/thread)
__global__ __launch_bounds__(256) void scan_k(const unsigned* __restrict__ T,
                                              unsigned* __restrict__ B) {
    __shared__ unsigned part[256];
    const int t = threadIdx.x;
    unsigned sum = 0;
    for (int k = 0; k < 64; ++k) sum += T[t * 64 + k];
    part[t] = sum;
    __syncthreads();
    for (int off = 1; off < 256; off <<= 1) {
        const unsigned v = (t >= off) ? part[t - off] : 0u;
        __syncthreads();
        part[t] += v;
        __syncthreads();
    }
    unsigned run = (t > 0) ? part[t - 1] : 0u;
    for (int k = 0; k < 64; ++k) {
        B[t * 64 + k] = run;
        run += T[t * 64 + k];
    }
}

// Pass 3: scatter ONE packed float4 record per point (LDS cursors)
__global__ __launch_bounds__(STHR) void scatter_k(const float2* __restrict__ coords,
                                                  const unsigned* __restrict__ C32,
                                                  const unsigned* __restrict__ P,
                                                  const unsigned* __restrict__ B,
                                                  float4* __restrict__ pts4) {
    __shared__ unsigned off[NBUCK];   // 64 KB cursors
    const int t = threadIdx.x;
    const int w = blockIdx.x;
    const int seg = w / WSEG;
    #pragma unroll
    for (int i4 = t; i4 < NB4; i4 += STHR) {
        const unsigned wrd = C32[(size_t)w * NB4 + i4];
        #pragma unroll
        for (int j = 0; j < 4; ++j) {
            const int b = 4 * i4 + j;
            off[b] = B[b] + P[(size_t)seg * NBUCK + b] + ((wrd >> (8 * j)) & 255u);
        }
    }
    __syncthreads();
    #pragma unroll
    for (int k = 0; k < SITER; ++k) {
        const int p = w * SPB + k * STHR + t;
        const float2 c = coords[p];
        const unsigned b = bucket_of(c.x, c.y);
        const unsigned pos = atomicAdd(&off[b], 1u);
        float4 rec;
        rec.x = c.x; rec.y = c.y;
        rec.z = __uint_as_float((unsigned)p);
        rec.w = 0.f;
        pts4[pos] = rec;
    }
}

__global__ __launch_bounds__(256, 4) void ngp_mfma(
    const float4* __restrict__ pts4,     // packed sorted records, or nullptr
    const float2* __restrict__ coords,   // raw coords (fallback)
    const float* __restrict__ hashf,
    const uint4* __restrict__ wbuf,
    const float* __restrict__ b0,
    const float* __restrict__ b1,
    const float* __restrict__ b2p,
    float* __restrict__ out, ResArr res)
{
    // single staging buffer, reused hi-then-lo; wave-private rows -> no barriers
    __shared__ unsigned short X[256 * XSTRIDE];

    const unsigned nwg = gridDim.x;
    const unsigned chunk = nwg >> 3;
    const unsigned sb = (blockIdx.x & 7u) * chunk + (blockIdx.x >> 3);
    const int tid = threadIdx.x;
    const int p = (int)(sb * 256u) + tid;

    float2 c;
    if (pts4) {
        const float4 rec = pts4[p];
        c.x = rec.x; c.y = rec.y;
    } else {
        c = coords[p];
    }

    // ---- interp: 4 software-pipelined chunks of 4 levels ----
    float f[32];
    float2 vA[16], vB[16];
    float2 wA[4], wB[4];

    auto issue = [&](int ck, float2* vv, float2* ww) {
        #pragma unroll
        for (int j = 0; j < 4; ++j) {
            const int r = ck * 4 + j;
            const float rr = res.r[r];
            const float x = c.x * rr;
            const float y = c.y * rr;
            const float xf = floorf(x);
            const float yf = floorf(y);
            ww[j].x = x - xf;
            ww[j].y = y - yf;
            const unsigned x0 = (unsigned)xf;
            const unsigned y0 = (unsigned)yf;
            const unsigned hy0 = PRIME_H * y0;
            const unsigned hy1 = PRIME_H * (y0 + 1u);
            const float2* tab = (const float2*)hashf + ((size_t)r << 19);
            vv[4*j+0] = tab[(x0 ^ hy0) & N_MASK];
            vv[4*j+1] = tab[(x0 ^ hy1) & N_MASK];
            vv[4*j+2] = tab[((x0 + 1u) ^ hy0) & N_MASK];
            vv[4*j+3] = tab[((x0 + 1u) ^ hy1) & N_MASK];
        }
    };
    auto consume = [&](int ck, const float2* vv, const float2* ww) {
        #pragma unroll
        for (int j = 0; j < 4; ++j) {
            const int r = ck * 4 + j;
            const float wx = ww[j].x, wy = ww[j].y;
            const float w00 = (1.f - wx) * (1.f - wy);
            const float w01 = (1.f - wx) * wy;
            const float w10 = wx * (1.f - wy);
            const float w11 = wx * wy;
            f[2*r+0] = vv[4*j+0].x*w00 + vv[4*j+1].x*w01 + vv[4*j+2].x*w10 + vv[4*j+3].x*w11;
            f[2*r+1] = vv[4*j+0].y*w00 + vv[4*j+1].y*w01 + vv[4*j+2].y*w10 + vv[4*j+3].y*w11;
        }
    };

    issue(0, vA, wA);
    issue(1, vB, wB);
    consume(0, vA, wA);
    issue(2, vA, wA);
    consume(1, vB, wB);
    issue(3, vB, wB);
    consume(2, vA, wA);
    consume(3, vB, wB);

    const int lane = tid & 63;
    const int wv   = tid >> 6;
    const int l31  = lane & 31;
    const int h    = lane >> 5;
    const int tb0  = wv * 64;
    const int tb1  = wv * 64 + 32;
    const int rowo = tid * XSTRIDE;

    auto ldx = [&](int ptl, int kc) -> FragU {
        FragU r;
        const int off = ptl * XSTRIDE + kc * 16 + h * 4;
        r.u2[0] = *(const uint2*)&X[off];
        r.u2[1] = *(const uint2*)&X[off + 8];
        return r;
    };

    // ---- pass 1: stage hi, read hi fragments ----
    #pragma unroll
    for (int q = 0; q < 8; ++q) {
        uint2 ph;
        ph.x = pack_hi(f[4*q+0], f[4*q+1]);
        ph.y = pack_hi(f[4*q+2], f[4*q+3]);
        *(uint2*)&X[rowo + 4*q] = ph;
    }
    FragU Ah0 = ldx(tb0 + l31, 0);
    FragU Ah1 = ldx(tb0 + l31, 1);
    FragU Bh0 = ldx(tb1 + l31, 0);
    FragU Bh1 = ldx(tb1 + l31, 1);

    // ---- pass 2: stage lo (same rows), read lo fragments ----
    #pragma unroll
    for (int q = 0; q < 8; ++q) {
        uint2 pl;
        pl.x = pack_lo(f[4*q+0], f[4*q+1]);
        pl.y = pack_lo(f[4*q+2], f[4*q+3]);
        *(uint2*)&X[rowo + 4*q] = pl;
    }
    FragU Al0 = ldx(tb0 + l31, 0);
    FragU Al1 = ldx(tb0 + l31, 1);
    FragU Bl0 = ldx(tb1 + l31, 0);
    FragU Bl1 = ldx(tb1 + l31, 1);

    // a[4q+j] = b[8q + 4h + j]
    auto bias_init = [&](const float* b) -> f32x16 {
        f32x16 a;
        #pragma unroll
        for (int q = 0; q < 4; ++q) {
            const float4 t = *(const float4*)(b + 8*q + 4*h);
            a[4*q+0] = t.x; a[4*q+1] = t.y; a[4*q+2] = t.z; a[4*q+3] = t.w;
        }
        return a;
    };

    f32x16 a0, a1;

    auto layer = [&](int l, const float* b) {
        FragU wh0, wl0, wh1, wl1;
        wh0.q = wbuf[(l*2+0)*64 + lane];
        wl0.q = wbuf[NFRAG + (l*2+0)*64 + lane];
        wh1.q = wbuf[(l*2+1)*64 + lane];
        wl1.q = wbuf[NFRAG + (l*2+1)*64 + lane];
        f32x16 A0 = bias_init(b);
        f32x16 A1 = A0;
        A0 = __builtin_amdgcn_mfma_f32_32x32x16_bf16(wh0.v, Ah0.v, A0, 0, 0, 0);
        A0 = __builtin_amdgcn_mfma_f32_32x32x16_bf16(wh0.v, Al0.v, A0, 0, 0, 0);
        A0 = __builtin_amdgcn_mfma_f32_32x32x16_bf16(wl0.v, Ah0.v, A0, 0, 0, 0);
        A0 = __builtin_amdgcn_mfma_f32_32x32x16_bf16(wh1.v, Ah1.v, A0, 0, 0, 0);
        A0 = __builtin_amdgcn_mfma_f32_32x32x16_bf16(wh1.v, Al1.v, A0, 0, 0, 0);
        A0 = __builtin_amdgcn_mfma_f32_32x32x16_bf16(wl1.v, Ah1.v, A0, 0, 0, 0);
        A1 = __builtin_amdgcn_mfma_f32_32x32x16_bf16(wh0.v, Bh0.v, A1, 0, 0, 0);
        A1 = __builtin_amdgcn_mfma_f32_32x32x16_bf16(wh0.v, Bl0.v, A1, 0, 0, 0);
        A1 = __builtin_amdgcn_mfma_f32_32x32x16_bf16(wl0.v, Bh0.v, A1, 0, 0, 0);
        A1 = __builtin_amdgcn_mfma_f32_32x32x16_bf16(wh1.v, Bh1.v, A1, 0, 0, 0);
        A1 = __builtin_amdgcn_mfma_f32_32x32x16_bf16(wh1.v, Bl1.v, A1, 0, 0, 0);
        A1 = __builtin_amdgcn_mfma_f32_32x32x16_bf16(wl1.v, Bh1.v, A1, 0, 0, 0);
        a0 = A0; a1 = A1;
    };

    // leaky + hi/lo repack in-register: D reg e -> kc0 frag elem e; reg 8+e -> kc1 elem e
    auto act_repack = [&](const f32x16& a, FragU& xh0, FragU& xl0, FragU& xh1, FragU& xl1) {
        float v[16];
        #pragma unroll
        for (int r = 0; r < 16; ++r) v[r] = fmaxf(a[r], 0.01f * a[r]);
        #pragma unroll
        for (int w = 0; w < 4; ++w) {
            xh0.u[w] = pack_hi(v[2*w],   v[2*w+1]);
            xl0.u[w] = pack_lo(v[2*w],   v[2*w+1]);
            xh1.u[w] = pack_hi(v[8+2*w], v[8+2*w+1]);
            xl1.u[w] = pack_lo(v[8+2*w], v[8+2*w+1]);
        }
    };

    layer(0, b0);
    act_repack(a0, Ah0, Al0, Ah1, Al1);
    act_repack(a1, Bh0, Bl0, Bh1, Bl1);
    layer(1, b1);
    act_repack(a0, Ah0, Al0, Ah1, Al1);
    act_repack(a1, Bh0, Bl0, Bh1, Bl1);
    layer(2, b2p);

    if (h == 0) {
        const int pl0 = (int)(sb * 256u) + tb0 + l31;
        const int pl1 = (int)(sb * 256u) + tb1 + l31;
        unsigned o0, o1;
        if (pts4) {
            o0 = __float_as_uint(((const float*)pts4)[4 * pl0 + 2]);
            o1 = __float_as_uint(((const float*)pts4)[4 * pl1 + 2]);
        } else {
            o0 = (unsigned)pl0;
            o1 = (unsigned)pl1;
        }
        out[(size_t)o0*3 + 0] = a0[0];
        out[(size_t)o0*3 + 1] = a0[1];
        out[(size_t)o0*3 + 2] = a0[2];
        out[(size_t)o1*3 + 0] = a1[0];
        out[(size_t)o1*3 + 1] = a1[1];
        out[(size_t)o1*3 + 2] = a1[2];
    }
}

extern "C" void kernel_launch(void* const* d_in, const int* in_sizes, int n_in,
                              void* d_out, int out_size, void* d_ws, size_t ws_size,
                              hipStream_t stream) {
    ResArr res;
    for (int i = 0; i < R_LEVELS; ++i)
        res.r[i] = (float)nearbyint(exp2(4.0 + (7.0 / 15.0) * (double)i));
    res.r[0] = 16.f;
    res.r[R_LEVELS - 1] = 2048.f;

    const float2* coords = (const float2*)d_in[0];
    const float* hashf   = (const float*)d_in[1];
    const float* W0      = (const float*)d_in[2];
    const float* b0      = (const float*)d_in[3];
    const float* W1      = (const float*)d_in[4];
    const float* b1      = (const float*)d_in[5];
    const float* W2      = (const float*)d_in[6];
    const float* b2      = (const float*)d_in[7];
    float* out           = (float*)d_out;

    // ws: C32 u32[256*4096] | P u32[8*16384] | T | B | pts4 f4[M] | wbuf | b2p
    const size_t off_C    = 0;
    const size_t off_P    = off_C + (size_t)SBLK * NB4 * 4;         // 4 MB
    const size_t off_T    = off_P + (size_t)NSEG * NBUCK * 4;       // +512 KB
    const size_t off_B    = off_T + NBUCK * 4;
    const size_t off_p4   = off_B + NBUCK * 4;
    const size_t off_wbuf = off_p4 + (size_t)M_PTS * sizeof(float4);
    const size_t off_b2p  = off_wbuf + 2 * NFRAG * sizeof(uint4);
    const size_t need     = off_b2p + 32 * sizeof(float);
    const size_t need_min = 2 * NFRAG * sizeof(uint4) + 32 * sizeof(float);

    dim3 blockM(256);
    dim3 gridM(M_PTS / 256);

    if (ws_size >= need) {
        unsigned* C32  = (unsigned*)((char*)d_ws + off_C);
        unsigned* P    = (unsigned*)((char*)d_ws + off_P);
        unsigned* T    = (unsigned*)((char*)d_ws + off_T);
        unsigned* B    = (unsigned*)((char*)d_ws + off_B);
        float4*   pts4 = (float4*)((char*)d_ws + off_p4);
        uint4*    wbuf = (uint4*)((char*)d_ws + off_wbuf);
        float*    b2p  = (float*)((char*)d_ws + off_b2p);

        hipLaunchKernelGGL(hist_k,    dim3(SBLK), dim3(STHR), 0, stream,
                           coords, C32, W0, W1, W2, b2, wbuf, b2p);
        hipLaunchKernelGGL(scanw1_k,  dim3(NSEG * NB4 / 256), dim3(256), 0, stream, C32, P);
        hipLaunchKernelGGL(scanw2_k,  dim3(NBUCK / 256), dim3(256), 0, stream, P, T);
        hipLaunchKernelGGL(scan_k,    dim3(1), dim3(256), 0, stream, T, B);
        hipLaunchKernelGGL(scatter_k, dim3(SBLK), dim3(STHR), 0, stream,
                           coords, C32, P, B, pts4);
        hipLaunchKernelGGL(ngp_mfma,  gridM, blockM, 0, stream,
                           pts4, coords, hashf, wbuf, b0, b1, b2p, out, res);
    } else if (ws_size >= need_min) {
        uint4* wbuf = (uint4*)d_ws;
        float* b2p  = (float*)((char*)d_ws + 2 * NFRAG * sizeof(uint4));
        hipLaunchKernelGGL(wprep_k,   dim3(1), dim3(384), 0, stream, W0, W1, W2, b2, wbuf, b2p);
        hipLaunchKernelGGL(ngp_mfma,  gridM, blockM, 0, stream,
                           (const float4*)nullptr, coords, hashf, wbuf, b0, b1, b2p, out, res);
    }
}